// Round 1
// baseline (736.881 us; speedup 1.0000x reference)
//
#include <hip/hip_runtime.h>
#include <hip/hip_bf16.h>

#define B_    1024
#define C_    896
#define N_    49
#define NN    2401
#define HD    128
#define NH    7
#define CQK   1792      // only q,k rows of W are used
#define KTOP  2160      // int(2401*0.9)
#define SCALE 0.08838834764831845f  // 128^-0.5

typedef short bf16x8 __attribute__((ext_vector_type(8)));
typedef float f32x4  __attribute__((ext_vector_type(4)));

__device__ __forceinline__ unsigned short f2bf(float f) {
  unsigned int u = __builtin_bit_cast(unsigned int, f);
  u += 0x7FFFu + ((u >> 16) & 1u);          // RNE
  return (unsigned short)(u >> 16);
}

// ---------------- kernel 1: W (first 1792 rows) -> bf16 ----------------
__global__ void k_convW(const float* __restrict__ W, unsigned short* __restrict__ Wbf) {
  int i = blockIdx.x * 256 + threadIdx.x;
  if (i < CQK * C_) Wbf[i] = f2bf(W[i]);
}

// ---------------- kernel 2: fused attention, one block per batch ----------------
#define T_STRIDE  904                      // 896 + 8 bf16 pad (2-way banks on A reads)
#define QK_STRIDE 264                      // 256 + 8 pad
#define LG_STRIDE 52
#define SM_T_OFF  0
#define SM_QK_OFF (49 * T_STRIDE * 2)                  // 88592
#define SM_LG_OFF (SM_QK_OFF + 49 * QK_STRIDE * 2)     // 114464
#define SM_FU_OFF (SM_LG_OFF + 64 * LG_STRIDE * 4)     // 127776
#define SM_TOTAL  (SM_FU_OFF + 49 * LG_STRIDE * 4)     // 137968 (<160K)

__global__ __launch_bounds__(512) void k_attn(const float* __restrict__ x,
                                              const unsigned short* __restrict__ Wbf,
                                              float* __restrict__ fusedg) {
  extern __shared__ char smem[];
  unsigned short* T  = (unsigned short*)(smem + SM_T_OFF);   // [49][904] tokens bf16
  unsigned short* QK = (unsigned short*)(smem + SM_QK_OFF);  // [49][264] q|k bf16
  float*          LG = (float*)(smem + SM_LG_OFF);           // [64][52] logits
  float*          FU = (float*)(smem + SM_FU_OFF);           // [49][52] min-over-heads

  const int b    = blockIdx.x;
  const int tid  = threadIdx.x;
  const int wid  = tid >> 6;
  const int lane = tid & 63;
  const int lrow = lane & 15;
  const int lk   = (lane >> 4) * 8;

  // stage tokens transposed: T[n][c] = x[b][c][n], coalesced global reads
  const float* xb = x + (size_t)b * (C_ * N_);
  for (int i = tid; i < C_ * N_; i += 512) {
    int c = i / N_;
    int n = i - c * N_;
    T[n * T_STRIDE + c] = f2bf(xb[i]);
  }
  __syncthreads();

  // A-fragment row offsets (rows >=49 clamped; results discarded by write guards)
  int rA[4];
#pragma unroll
  for (int m = 0; m < 4; ++m) {
    int r = 16 * m + lrow; if (r > 48) r = 48;
    rA[m] = r * T_STRIDE + lk;
  }

  const int nt0 = wid * 2;   // each wave owns 2 of the 16 n-tiles (256 cols of QK)
  const f32x4 z = {0.f, 0.f, 0.f, 0.f};

  for (int h = 0; h < NH; ++h) {
    // ---- step A: QK[49x256] = T[49x896] * W_h^T ----
    f32x4 acc[4][2];
#pragma unroll
    for (int m = 0; m < 4; ++m) { acc[m][0] = z; acc[m][1] = z; }

    const unsigned short* wp[2];
#pragma unroll
    for (int n = 0; n < 2; ++n) {
      int nt = nt0 + n;
      int grow = (nt < 8) ? (h * HD + nt * 16 + lrow)
                          : (C_ + h * HD + (nt - 8) * 16 + lrow);
      wp[n] = Wbf + (size_t)grow * C_ + lk;
    }
    for (int k0 = 0; k0 < C_; k0 += 32) {
      bf16x8 a[4], bb[2];
#pragma unroll
      for (int m = 0; m < 4; ++m) a[m] = *(const bf16x8*)(T + rA[m] + k0);
#pragma unroll
      for (int n = 0; n < 2; ++n) bb[n] = *(const bf16x8*)(wp[n] + k0);
#pragma unroll
      for (int m = 0; m < 4; ++m)
#pragma unroll
        for (int n = 0; n < 2; ++n)
          acc[m][n] = __builtin_amdgcn_mfma_f32_16x16x32_bf16(a[m], bb[n], acc[m][n], 0, 0, 0);
    }
#pragma unroll
    for (int m = 0; m < 4; ++m)
#pragma unroll
      for (int r = 0; r < 4; ++r) {
        int mr = m * 16 + (lane >> 4) * 4 + r;
        if (mr < N_) {
#pragma unroll
          for (int n = 0; n < 2; ++n)
            QK[mr * QK_STRIDE + (nt0 + n) * 16 + lrow] = f2bf(acc[m][n][r]);
        }
      }
    __syncthreads();

    // ---- step B: logits L[49x49] = Q * K^T ----
    f32x4 acc2[2] = {z, z};
    int mt[2], ntt[2], rowA[2], rowB[2];
#pragma unroll
    for (int i = 0; i < 2; ++i) {
      int t = wid * 2 + i; mt[i] = t >> 2; ntt[i] = t & 3;
      int ra = mt[i] * 16 + lrow;  if (ra > 48) ra = 48;
      int rb = ntt[i] * 16 + lrow; if (rb > 48) rb = 48;
      rowA[i] = ra * QK_STRIDE + lk;
      rowB[i] = rb * QK_STRIDE + HD + lk;
    }
    for (int e0 = 0; e0 < HD; e0 += 32) {
#pragma unroll
      for (int i = 0; i < 2; ++i) {
        bf16x8 a  = *(const bf16x8*)(QK + rowA[i] + e0);
        bf16x8 bb = *(const bf16x8*)(QK + rowB[i] + e0);
        acc2[i] = __builtin_amdgcn_mfma_f32_16x16x32_bf16(a, bb, acc2[i], 0, 0, 0);
      }
    }
#pragma unroll
    for (int i = 0; i < 2; ++i)
#pragma unroll
      for (int r = 0; r < 4; ++r) {
        int row = mt[i] * 16 + (lane >> 4) * 4 + r;
        int col = ntt[i] * 16 + lrow;
        if (col < N_) LG[row * LG_STRIDE + col] = acc2[i][r] * SCALE;
      }
    __syncthreads();

    // ---- softmax rows + min-over-heads accumulate ----
    for (int r = wid; r < N_; r += 8) {
      float v = (lane < N_) ? LG[r * LG_STRIDE + lane] : -1e30f;
      float mx = v;
#pragma unroll
      for (int off = 32; off >= 1; off >>= 1) mx = fmaxf(mx, __shfl_xor(mx, off));
      float e = (lane < N_) ? __expf(v - mx) : 0.f;
      float s = e;
#pragma unroll
      for (int off = 32; off >= 1; off >>= 1) s += __shfl_xor(s, off);
      float p = e / s;
      if (lane < N_) {
        float cur = (h == 0) ? p : fminf(FU[r * LG_STRIDE + lane], p);
        if (h < NH - 1) FU[r * LG_STRIDE + lane] = cur;
        else            fusedg[(size_t)b * NN + r * N_ + lane] = cur;
      }
    }
    __syncthreads();
  }
}

// ---------------- kernel 3: per-batch bottom-2160 threshold + union mask ----------------
__global__ void k_select(const float* __restrict__ fusedg, unsigned int* __restrict__ gmask) {
  __shared__ unsigned int v[NN];
  __shared__ unsigned int lmask[76];
  __shared__ int cnt;
  const int b = blockIdx.x, t = threadIdx.x;
  for (int p = t; p < NN; p += 256)
    v[p] = __builtin_bit_cast(unsigned int, fusedg[(size_t)b * NN + p]);
  for (int p = t; p < 76; p += 256) lmask[p] = 0u;
  __syncthreads();

  // binary search on bits: largest u with count(v < u) < KTOP  => member iff v <= u
  unsigned int u = 0;
  for (int bit = 30; bit >= 0; --bit) {
    unsigned int cand = u | (1u << bit);
    if (t == 0) cnt = 0;
    __syncthreads();
    int c = 0;
    for (int p = t; p < NN; p += 256) c += (v[p] < cand) ? 1 : 0;
    atomicAdd(&cnt, c);
    __syncthreads();
    if (cnt < KTOP) u = cand;
    __syncthreads();
  }
  for (int p = t; p < NN; p += 256)
    if (p != 0 && v[p] <= u) atomicOr(&lmask[p >> 5], 1u << (p & 31));
  __syncthreads();
  for (int p = t; p < 76; p += 256)
    if (lmask[p]) atomicOr(&gmask[p], lmask[p]);
}

// ---------------- kernel 4: apply union mask to batch 0 only ----------------
__global__ void k_mask0(float* __restrict__ fusedg, const unsigned int* __restrict__ gmask) {
  for (int p = threadIdx.x; p < NN; p += 256)
    if ((gmask[p >> 5] >> (p & 31)) & 1u) fusedg[p] = 0.f;
}

// ---------------- kernel 5: rollout collapses to row/col sums ----------------
__global__ void k_rollout(const float* __restrict__ fusedg, float* __restrict__ att) {
  __shared__ float fl[NN];
  const int b = blockIdx.x, t = threadIdx.x;
  for (int p = t; p < NN; p += 256) fl[p] = fusedg[(size_t)b * NN + p];
  __syncthreads();
  if (t < N_) {
    float rs = 0.f, cs = 0.f;
    for (int m = 0; m < N_; ++m) { rs += fl[t * N_ + m]; cs += fl[m * N_ + t]; }
    att[b * N_ + t] = (cs + 1.0f) / (49.0f * (rs + 1.0f));
  }
}

// ---------------- kernel 6: rx = x * (1 + att[b,n]) ----------------
__global__ void k_rx(const float* __restrict__ x, const float* __restrict__ att,
                     float* __restrict__ out) {
  const long total4 = (long)B_ * C_ * N_ / 4;
  for (long g = (long)blockIdx.x * 256 + threadIdx.x; g < total4; g += (long)gridDim.x * 256) {
    long e0 = g * 4;
    int b = (int)(e0 / (C_ * N_));
    int r = (int)(e0 - (long)b * (C_ * N_));
    int n = r % N_;
    const float4 xv = ((const float4*)x)[g];
    const float* ab = att + b * N_;
    float a0 = ab[n];
    int n1 = n + 1;  if (n1 == N_) n1 = 0;  float a1 = ab[n1];
    int n2 = n1 + 1; if (n2 == N_) n2 = 0;  float a2 = ab[n2];
    int n3 = n2 + 1; if (n3 == N_) n3 = 0;  float a3 = ab[n3];
    float4 o;
    o.x = xv.x * (1.f + a0); o.y = xv.y * (1.f + a1);
    o.z = xv.z * (1.f + a2); o.w = xv.w * (1.f + a3);
    ((float4*)out)[g] = o;
  }
}

extern "C" void kernel_launch(void* const* d_in, const int* in_sizes, int n_in,
                              void* d_out, int out_size, void* d_ws, size_t ws_size,
                              hipStream_t stream) {
  const float* x = (const float*)d_in[0];
  const float* W = (const float*)d_in[1];
  float* out = (float*)d_out;
  char* ws = (char*)d_ws;

  float*          fused = (float*)ws;                        //  9,834,496 B
  float*          att   = (float*)(ws + 9834496);            //    200,704 B
  unsigned short* Wbf   = (unsigned short*)(ws + 10035200);  //  3,211,264 B
  unsigned int*   gmask = (unsigned int*)(ws + 13246464);    //        304 B

  hipMemsetAsync(gmask, 0, 76 * sizeof(unsigned int), stream);
  k_convW<<<(CQK * C_ + 255) / 256, 256, 0, stream>>>(W, Wbf);

  hipFuncSetAttribute((const void*)k_attn, hipFuncAttributeMaxDynamicSharedMemorySize, SM_TOTAL);
  k_attn<<<B_, 512, SM_TOTAL, stream>>>(x, Wbf, fused);

  k_select<<<B_, 256, 0, stream>>>(fused, gmask);
  k_mask0<<<1, 256, 0, stream>>>(fused, gmask);
  k_rollout<<<B_, 256, 0, stream>>>(fused, att);
  k_rx<<<2048, 256, 0, stream>>>(x, att, out);
}